// Round 4
// baseline (2517.522 us; speedup 1.0000x reference)
//
#include <hip/hip_runtime.h>

#define N_X  40000
#define NN   50000
#define NE   800000
#define MPAD 50048

using short8  = __attribute__((ext_vector_type(8))) short;
using floatx4 = __attribute__((ext_vector_type(4))) float;

typedef const __attribute__((address_space(1))) void gv_t;
typedef __attribute__((address_space(3))) void lv_t;

__device__ __forceinline__ unsigned short f2bf(float f) {
  unsigned u = __float_as_uint(f);
  u += 0x7FFF + ((u >> 16) & 1);           // RNE
  return (unsigned short)(u >> 16);
}
__device__ __forceinline__ float bf2f(unsigned v) {
  return __uint_as_float(v << 16);
}

// ---------------- preprocessing ----------------
__global__ void k_deg(const int* __restrict__ dst, int* __restrict__ deg) {
  int e = blockIdx.x * blockDim.x + threadIdx.x;
  if (e < NE) atomicAdd(&deg[dst[e]], 1);
}

__global__ void k_dis(const int* __restrict__ deg, float* __restrict__ dis) {
  int i = blockIdx.x * blockDim.x + threadIdx.x;
  if (i < NN) dis[i] = deg[i] > 0 ? rsqrtf((float)deg[i]) : 0.f;
}

#define SCAN_B 1024
#define SCAN_NB 49
__global__ void k_scan1(const int* __restrict__ deg, int* __restrict__ rowp,
                        int* __restrict__ bsum) {
  __shared__ int buf[SCAN_B];
  int b = blockIdx.x;
  int i = b * SCAN_B + threadIdx.x;
  int v = (i < NN) ? deg[i] : 0;
  buf[threadIdx.x] = v;
  __syncthreads();
  for (int off = 1; off < SCAN_B; off <<= 1) {
    int t = (threadIdx.x >= off) ? buf[threadIdx.x - off] : 0;
    __syncthreads();
    buf[threadIdx.x] += t;
    __syncthreads();
  }
  if (i < NN) rowp[i] = buf[threadIdx.x] - v;   // block-local exclusive
  if (threadIdx.x == SCAN_B - 1) bsum[b] = buf[SCAN_B - 1];
}

__global__ void k_scan2(int* __restrict__ bsum) {
  if (threadIdx.x == 0) {
    int acc = 0;
    for (int i = 0; i < SCAN_NB; ++i) { int t = bsum[i]; bsum[i] = acc; acc += t; }
  }
}

__global__ void k_scan3(int* __restrict__ rowp, const int* __restrict__ bsum) {
  int i = blockIdx.x * blockDim.x + threadIdx.x;
  if (i < NN) rowp[i] += bsum[i >> 10];
  if (i == 0) rowp[NN] = NE;
}

__global__ void k_build(const int* __restrict__ dst, const int* __restrict__ src,
                        const int* __restrict__ typ, const float* __restrict__ dis,
                        const int* __restrict__ rowp, int* __restrict__ cur,
                        unsigned* __restrict__ est, float* __restrict__ ewt) {
  int e = blockIdx.x * blockDim.x + threadIdx.x;
  if (e >= NE) return;
  int d = dst[e], s = src[e];
  int p = rowp[d] + atomicAdd(&cur[d], 1);
  est[p] = (unsigned)s | ((unsigned)typ[e] << 28);
  ewt[p] = dis[d] * dis[s];
}

// ---------------- per-layer kernels ----------------
__global__ void k_prep0(const float* __restrict__ x, const float* __restrict__ emb,
                        unsigned short* __restrict__ Xh, unsigned short* __restrict__ Xl,
                        int xs) {
  int idx = blockIdx.x * blockDim.x + threadIdx.x;
  if (idx >= NN * 32) return;
  int r = idx >> 5, c4 = (idx & 31) * 4;
  const float* srcp = (r < N_X) ? (x + (size_t)r * 128 + c4)
                                : (emb + (size_t)(r - N_X) * 128 + c4);
  float4 hv = *(const float4*)srcp;
  float vv[4] = {hv.x, hv.y, hv.z, hv.w};
  unsigned hw[2], lw[2];
#pragma unroll
  for (int q = 0; q < 2; ++q) {
    unsigned short h0 = f2bf(vv[2 * q]), h1 = f2bf(vv[2 * q + 1]);
    unsigned short l0 = f2bf(vv[2 * q] - bf2f(h0)), l1 = f2bf(vv[2 * q + 1] - bf2f(h1));
    hw[q] = (unsigned)h0 | ((unsigned)h1 << 16);
    lw[q] = (unsigned)l0 | ((unsigned)l1 << 16);
  }
  size_t o = (size_t)r * xs + c4;
  *(uint2*)(Xh + o) = make_uint2(hw[0], hw[1]);
  *(uint2*)(Xl + o) = make_uint2(lw[0], lw[1]);
}

__global__ void k_prep(const float* __restrict__ H, const float* __restrict__ sc,
                       const float* __restrict__ sh, unsigned short* __restrict__ Xh,
                       unsigned short* __restrict__ Xl, int din, int logq, int xs) {
  int idx = blockIdx.x * blockDim.x + threadIdx.x;
  if (idx >= NN * (din >> 2)) return;
  int r = idx >> logq, c4 = (idx & ((din >> 2) - 1)) * 4;
  float4 hv = *(const float4*)(H + (size_t)r * din + c4);
  float vv[4] = {hv.x, hv.y, hv.z, hv.w};
  unsigned hw[2], lw[2];
#pragma unroll
  for (int q = 0; q < 4; ++q)
    vv[q] = fmaxf(vv[q] * sc[c4 + q] + sh[c4 + q], 0.f);
#pragma unroll
  for (int q = 0; q < 2; ++q) {
    unsigned short h0 = f2bf(vv[2 * q]), h1 = f2bf(vv[2 * q + 1]);
    unsigned short l0 = f2bf(vv[2 * q] - bf2f(h0)), l1 = f2bf(vv[2 * q + 1] - bf2f(h1));
    hw[q] = (unsigned)h0 | ((unsigned)h1 << 16);
    lw[q] = (unsigned)l0 | ((unsigned)l1 << 16);
  }
  size_t o = (size_t)r * xs + c4;
  *(uint2*)(Xh + o) = make_uint2(hw[0], hw[1]);
  *(uint2*)(Xl + o) = make_uint2(lw[0], lw[1]);
}

// one WAVE per node; L lanes per edge (L = din/8), 64/L edges in flight
template <int L>
__global__ void k_agg(unsigned short* __restrict__ Xh, unsigned short* __restrict__ Xl,
                      const int* __restrict__ rowp, const unsigned* __restrict__ est,
                      const float* __restrict__ ewt, int xs) {
  constexpr int G = 64 / L;
  constexpr int din = L * 8;
  const int wid = (blockIdx.x * 256 + threadIdx.x) >> 6;
  if (wid >= NN) return;
  const int lane = threadIdx.x & 63;
  const int grp = lane / L;
  const int j = lane & (L - 1);
  const int c0 = j * 8;
  const int beg = rowp[wid], end = rowp[wid + 1];
  float a0[8] = {}, a1[8] = {}, a2[8] = {};
  for (int i = beg + grp; i < end; i += G) {
    const unsigned st = est[i];
    const float wv = ewt[i];
    const size_t off = (size_t)(st & 0x0FFFFFFFu) * xs + c0;
    const unsigned t = st >> 28;
    uint4 hr = *(const uint4*)(Xh + off);
    uint4 lr = *(const uint4*)(Xl + off);
    float v[8];
    v[0] = bf2f(hr.x & 0xFFFFu) + bf2f(lr.x & 0xFFFFu);
    v[1] = bf2f(hr.x >> 16)     + bf2f(lr.x >> 16);
    v[2] = bf2f(hr.y & 0xFFFFu) + bf2f(lr.y & 0xFFFFu);
    v[3] = bf2f(hr.y >> 16)     + bf2f(lr.y >> 16);
    v[4] = bf2f(hr.z & 0xFFFFu) + bf2f(lr.z & 0xFFFFu);
    v[5] = bf2f(hr.z >> 16)     + bf2f(lr.z >> 16);
    v[6] = bf2f(hr.w & 0xFFFFu) + bf2f(lr.w & 0xFFFFu);
    v[7] = bf2f(hr.w >> 16)     + bf2f(lr.w >> 16);
    if (t == 0) {
#pragma unroll
      for (int q = 0; q < 8; ++q) a0[q] += wv * v[q];
    } else if (t == 1) {
#pragma unroll
      for (int q = 0; q < 8; ++q) a1[q] += wv * v[q];
    } else {
#pragma unroll
      for (int q = 0; q < 8; ++q) a2[q] += wv * v[q];
    }
  }
#pragma unroll
  for (int off = L; off < 64; off <<= 1) {
#pragma unroll
    for (int q = 0; q < 8; ++q) {
      a0[q] += __shfl_xor(a0[q], off);
      a1[q] += __shfl_xor(a1[q], off);
      a2[q] += __shfl_xor(a2[q], off);
    }
  }
  if (grp == 0) {
    const size_t ob = (size_t)wid * xs + din + c0;
    auto store8 = [&](const float* a, size_t o) {
      unsigned hw[4], lw[4];
#pragma unroll
      for (int q = 0; q < 4; ++q) {
        unsigned short h0 = f2bf(a[2 * q]), h1 = f2bf(a[2 * q + 1]);
        unsigned short l0 = f2bf(a[2 * q] - bf2f(h0)), l1 = f2bf(a[2 * q + 1] - bf2f(h1));
        hw[q] = (unsigned)h0 | ((unsigned)h1 << 16);
        lw[q] = (unsigned)l0 | ((unsigned)l1 << 16);
      }
      *(uint4*)(Xh + o) = make_uint4(hw[0], hw[1], hw[2], hw[3]);
      *(uint4*)(Xl + o) = make_uint4(lw[0], lw[1], lw[2], lw[3]);
    };
    store8(a0, ob);
    store8(a1, ob + din);
    store8(a2, ob + 2 * din);
  }
}

// WcT[n][k] hi/lo
__global__ void k_wcatT(const float* __restrict__ root, const float* __restrict__ W,
                        unsigned short* __restrict__ BhT, unsigned short* __restrict__ BlT,
                        int din, int dout) {
  int idx = blockIdx.x * blockDim.x + threadIdx.x;
  int K = 4 * din;
  if (idx >= dout * K) return;
  int n = idx / K, k = idx % K;
  float v = (k < din) ? root[(size_t)k * dout + n] : W[(size_t)(k - din) * dout + n];
  unsigned short h = f2bf(v);
  BhT[idx] = h;
  BlT[idx] = f2bf(v - bf2f(h));
}

// ---------------- split-f32 MFMA GEMM ----------------
// C = (Ah+Al) @ (Bh+Bl)^T + bias, tile 128 x BN, 4 waves (2x2)
// global_load_lds staging, depth-2 prefetch, counted vmcnt (T4), setprio (T5)
template <int BN>
__global__ __launch_bounds__(256, 3) void k_gemm_mfma(
    const unsigned short* __restrict__ Ah, const unsigned short* __restrict__ Al,
    const unsigned short* __restrict__ Bh, const unsigned short* __restrict__ Bl,
    const float* __restrict__ bias, float* __restrict__ C,
    int M, int K, int Nc, int ny) {
  constexpr int NCHB = BN / 16;        // B chunks per plane
  constexpr int TC = 16 + 2 * NCHB;    // 1KB chunks per buffer
  constexpr int CPW = TC / 4;          // chunks staged per wave
  constexpr int NT = BN / 32;          // n-frags per wave
  __shared__ __align__(16) char lds[2][TC * 1024];

  const int tid = threadIdx.x;
  const int lane = tid & 63;
  const int w = tid >> 6;
  const int wm = w >> 1, wn = w & 1;
  const int r16 = lane & 15, kg = lane >> 4;

  // bijective XCD swizzle (m204)
  const int nwg = gridDim.x;
  const int q = nwg >> 3, r = nwg & 7;
  const int xcd = blockIdx.x & 7, pos = blockIdx.x >> 3;
  const int t = (xcd < r ? xcd * (q + 1) : r * (q + 1) + (xcd - r) * q) + pos;
  const int bm = (t / ny) * 128;
  const int bn = (t % ny) * BN;

  const unsigned short* gb[CPW];
#pragma unroll
  for (int i = 0; i < CPW; ++i) {
    int c = w * CPW + i;
    const unsigned short* base;
    int row;
    if (c < 8)               { base = Ah; row = bm + c * 16; }
    else if (c < 16)         { base = Al; row = bm + (c - 8) * 16; }
    else if (c < 16 + NCHB)  { base = Bh; row = bn + (c - 16) * 16; }
    else                     { base = Bl; row = bn + (c - 16 - NCHB) * 16; }
    gb[i] = base + (size_t)(row + r16) * K + kg * 8;
  }

  floatx4 acc[4][NT];
#pragma unroll
  for (int i = 0; i < 4; ++i)
#pragma unroll
    for (int jj = 0; jj < NT; ++jj) acc[i][jj] = (floatx4)0.f;

  const int nk = K >> 5;

  auto stage = [&](int b, int tk) {
#pragma unroll
    for (int i = 0; i < CPW; ++i)
      __builtin_amdgcn_global_load_lds((gv_t*)(gb[i] + tk * 32),
                                       (lv_t*)&lds[b][(w * CPW + i) * 1024],
                                       16, 0, 0);
  };

  stage(0, 0);
  stage(1, 1);

  int buf = 0;
  for (int tk = 0; tk < nk; ++tk) {
    // wait only for tile tk's loads; tile tk+1's CPW loads stay in flight
    if (tk < nk - 1) {
      if constexpr (CPW == 6)       asm volatile("s_waitcnt vmcnt(6)" ::: "memory");
      else if constexpr (CPW == 8)  asm volatile("s_waitcnt vmcnt(8)" ::: "memory");
      else                          asm volatile("s_waitcnt vmcnt(0)" ::: "memory");
    } else {
      asm volatile("s_waitcnt vmcnt(0)" ::: "memory");
    }
    __builtin_amdgcn_s_barrier();

    const char* Lb = lds[buf];
    short8 ah[4], al[4], bh[NT], bl[NT];
#pragma unroll
    for (int mt = 0; mt < 4; ++mt) {
      ah[mt] = *(const short8*)(Lb + (wm * 4 + mt) * 1024 + lane * 16);
      al[mt] = *(const short8*)(Lb + (8 + wm * 4 + mt) * 1024 + lane * 16);
    }
#pragma unroll
    for (int nt = 0; nt < NT; ++nt) {
      bh[nt] = *(const short8*)(Lb + (16 + wn * NT + nt) * 1024 + lane * 16);
      bl[nt] = *(const short8*)(Lb + (16 + NCHB + wn * NT + nt) * 1024 + lane * 16);
    }

    __builtin_amdgcn_s_setprio(1);
#pragma unroll
    for (int mt = 0; mt < 4; ++mt)
#pragma unroll
      for (int nt = 0; nt < NT; ++nt) {
        acc[mt][nt] = __builtin_amdgcn_mfma_f32_16x16x32_bf16(ah[mt], bh[nt], acc[mt][nt], 0, 0, 0);
        acc[mt][nt] = __builtin_amdgcn_mfma_f32_16x16x32_bf16(ah[mt], bl[nt], acc[mt][nt], 0, 0, 0);
        acc[mt][nt] = __builtin_amdgcn_mfma_f32_16x16x32_bf16(al[mt], bh[nt], acc[mt][nt], 0, 0, 0);
      }
    __builtin_amdgcn_s_setprio(0);

    __builtin_amdgcn_s_barrier();     // all waves done reading lds[buf]
    if (tk + 2 < nk) stage(buf, tk + 2);
    buf ^= 1;
  }

  // D row = (lane>>4)*4 + reg, col = lane&15
#pragma unroll
  for (int mt = 0; mt < 4; ++mt) {
    const int gr0 = bm + wm * 64 + mt * 16 + kg * 4;
#pragma unroll
    for (int nt = 0; nt < NT; ++nt) {
      const int col = bn + wn * (NT * 16) + nt * 16 + r16;
      const float bv = bias[col];
#pragma unroll
      for (int rr = 0; rr < 4; ++rr) {
        const int gr = gr0 + rr;
        if (gr < M) C[(size_t)gr * Nc + col] = acc[mt][nt][rr] + bv;
      }
    }
  }
}

// ---------------- batch-norm stats ----------------
__global__ void k_bnstats(const float* __restrict__ H, float* __restrict__ sums, int d) {
  int c = threadIdx.x;
  float s = 0.f, s2 = 0.f;
  for (int r = blockIdx.x; r < NN; r += gridDim.x) {
    float v = H[(size_t)r * d + c];
    s += v;
    s2 += v * v;
  }
  atomicAdd(&sums[c], s);
  atomicAdd(&sums[d + c], s2);
}

__global__ void k_bnfinal(const float* __restrict__ sums, const float* __restrict__ g,
                          const float* __restrict__ b, float* __restrict__ sc,
                          float* __restrict__ sh, int d) {
  int c = threadIdx.x;
  if (c >= d) return;
  float mean = sums[c] * (1.f / NN);
  float var = sums[d + c] * (1.f / NN) - mean * mean;
  float rs = rsqrtf(var + 1e-5f);
  float s = rs * g[c];
  sc[c] = s;
  sh[c] = b[c] - mean * s;
}

// ---------------- host driver ----------------
extern "C" void kernel_launch(void* const* d_in, const int* in_sizes, int n_in,
                              void* d_out, int out_size, void* d_ws, size_t ws_size,
                              hipStream_t stream) {
  const float* x   = (const float*)d_in[0];
  const float* emb = (const float*)d_in[1];
  const float* conv_w[4] = {(const float*)d_in[2], (const float*)d_in[5],
                            (const float*)d_in[8], (const float*)d_in[11]};
  const float* conv_r[4] = {(const float*)d_in[3], (const float*)d_in[6],
                            (const float*)d_in[9], (const float*)d_in[12]};
  const float* conv_b[4] = {(const float*)d_in[4], (const float*)d_in[7],
                            (const float*)d_in[10], (const float*)d_in[13]};
  const float* n1g = (const float*)d_in[14];
  const float* n1b = (const float*)d_in[15];
  const float* n2g = (const float*)d_in[16];
  const float* n2b = (const float*)d_in[17];
  const int* eidx = (const int*)d_in[18];
  const int* etyp = (const int*)d_in[19];
  const int* dst  = eidx;
  const int* srcp = eidx + NE;
  float* out = (float*)d_out;

  char* w = (char*)d_ws;
  auto alloc = [&](size_t bytes) {
    char* p = w;
    w += (bytes + 255) & ~(size_t)255;
    return p;
  };
  unsigned short* Xh  = (unsigned short*)alloc((size_t)MPAD * 1024 * 2);
  unsigned short* Xl  = (unsigned short*)alloc((size_t)MPAD * 1024 * 2);
  float*    H    = (float*)alloc((size_t)NN * 256 * 4);
  unsigned short* WcTh = (unsigned short*)alloc((size_t)256 * 1024 * 2);
  unsigned short* WcTl = (unsigned short*)alloc((size_t)256 * 1024 * 2);
  float*    bns  = (float*)alloc(512 * 4);
  float*    bsc  = (float*)alloc(256 * 4);
  float*    bsh  = (float*)alloc(256 * 4);
  float*    dis  = (float*)alloc((size_t)NN * 4);
  int*      deg  = (int*)alloc((size_t)NN * 4);
  int*      rowp = (int*)alloc((size_t)(NN + 1) * 4);
  int*      cur  = (int*)alloc((size_t)NN * 4);
  int*      bsum = (int*)alloc(64 * 4);
  unsigned* est  = (unsigned*)alloc((size_t)NE * 4);
  float*    ewt  = (float*)alloc((size_t)NE * 4);

  hipMemsetAsync(deg, 0, (size_t)NN * 4, stream);
  hipMemsetAsync(cur, 0, (size_t)NN * 4, stream);
  k_deg<<<(NE + 255) / 256, 256, 0, stream>>>(dst, deg);
  k_dis<<<(NN + 255) / 256, 256, 0, stream>>>(deg, dis);
  k_scan1<<<SCAN_NB, SCAN_B, 0, stream>>>(deg, rowp, bsum);
  k_scan2<<<1, 64, 0, stream>>>(bsum);
  k_scan3<<<(NN + 255) / 256, 256, 0, stream>>>(rowp, bsum);
  k_build<<<(NE + 255) / 256, 256, 0, stream>>>(dst, srcp, etyp, dis, rowp, cur, est, ewt);

  const int din_a[8]  = {128, 128, 256, 256, 256, 256, 256, 256};
  const int dout_a[8] = {128, 256, 256, 256, 256, 256, 256, 64};
  const int wi_a[8]   = {0, 1, 2, 2, 2, 2, 2, 3};
  const int gm = (NN + 127) / 128;   // 391

  for (int l = 0; l < 8; ++l) {
    const int din = din_a[l], dout = dout_a[l];
    const int K = 4 * din, xs = K;
    const int wi = wi_a[l];

    if (l == 0)
      k_prep0<<<(NN * 32 + 255) / 256, 256, 0, stream>>>(x, emb, Xh, Xl, xs);
    else
      k_prep<<<(NN * (din >> 2) + 255) / 256, 256, 0, stream>>>(
          H, bsc, bsh, Xh, Xl, din, (din == 128 ? 5 : 6), xs);

    if (din == 128)
      k_agg<16><<<(NN + 3) / 4, 256, 0, stream>>>(Xh, Xl, rowp, est, ewt, xs);
    else
      k_agg<32><<<(NN + 3) / 4, 256, 0, stream>>>(Xh, Xl, rowp, est, ewt, xs);

    k_wcatT<<<(dout * K + 255) / 256, 256, 0, stream>>>(conv_r[wi], conv_w[wi], WcTh, WcTl, din, dout);

    float* C = (l == 7) ? out : H;
    const int ny = dout / 64;
    k_gemm_mfma<64><<<gm * ny, 256, 0, stream>>>(Xh, Xl, WcTh, WcTl, conv_b[wi], C, NN, K, dout, ny);

    if (l < 7) {
      hipMemsetAsync(bns, 0, (size_t)2 * dout * 4, stream);
      k_bnstats<<<256, dout, 0, stream>>>(H, bns, dout);
      k_bnfinal<<<1, 256, 0, stream>>>(bns, (l == 0) ? n1g : n2g,
                                       (l == 0) ? n1b : n2b, bsc, bsh, dout);
    }
  }
}

// Round 5
// 1847.737 us; speedup vs baseline: 1.3625x; 1.3625x over previous
//
#include <hip/hip_runtime.h>

#define N_X  40000
#define NN   50000
#define NE   800000
#define MPAD 50048

using short8  = __attribute__((ext_vector_type(8))) short;
using floatx4 = __attribute__((ext_vector_type(4))) float;

typedef const __attribute__((address_space(1))) void gv_t;
typedef __attribute__((address_space(3))) void lv_t;

__device__ __forceinline__ unsigned short f2bf(float f) {
  unsigned u = __float_as_uint(f);
  u += 0x7FFF + ((u >> 16) & 1);           // RNE
  return (unsigned short)(u >> 16);
}
__device__ __forceinline__ float bf2f(unsigned v) {
  return __uint_as_float(v << 16);
}

// ---------------- preprocessing ----------------
__global__ void k_deg(const int* __restrict__ dst, int* __restrict__ deg) {
  int e = blockIdx.x * blockDim.x + threadIdx.x;
  if (e < NE) atomicAdd(&deg[dst[e]], 1);
}

__global__ void k_dis(const int* __restrict__ deg, float* __restrict__ dis) {
  int i = blockIdx.x * blockDim.x + threadIdx.x;
  if (i < NN) dis[i] = deg[i] > 0 ? rsqrtf((float)deg[i]) : 0.f;
}

#define SCAN_B 1024
#define SCAN_NB 49
__global__ void k_scan1(const int* __restrict__ deg, int* __restrict__ rowp,
                        int* __restrict__ bsum) {
  __shared__ int buf[SCAN_B];
  int b = blockIdx.x;
  int i = b * SCAN_B + threadIdx.x;
  int v = (i < NN) ? deg[i] : 0;
  buf[threadIdx.x] = v;
  __syncthreads();
  for (int off = 1; off < SCAN_B; off <<= 1) {
    int t = (threadIdx.x >= off) ? buf[threadIdx.x - off] : 0;
    __syncthreads();
    buf[threadIdx.x] += t;
    __syncthreads();
  }
  if (i < NN) rowp[i] = buf[threadIdx.x] - v;   // block-local exclusive
  if (threadIdx.x == SCAN_B - 1) bsum[b] = buf[SCAN_B - 1];
}

__global__ void k_scan2(int* __restrict__ bsum) {
  if (threadIdx.x == 0) {
    int acc = 0;
    for (int i = 0; i < SCAN_NB; ++i) { int t = bsum[i]; bsum[i] = acc; acc += t; }
  }
}

__global__ void k_scan3(int* __restrict__ rowp, const int* __restrict__ bsum) {
  int i = blockIdx.x * blockDim.x + threadIdx.x;
  if (i < NN) rowp[i] += bsum[i >> 10];
  if (i == 0) rowp[NN] = NE;
}

__global__ void k_build(const int* __restrict__ dst, const int* __restrict__ src,
                        const int* __restrict__ typ, const float* __restrict__ dis,
                        const int* __restrict__ rowp, int* __restrict__ cur,
                        unsigned* __restrict__ est, float* __restrict__ ewt) {
  int e = blockIdx.x * blockDim.x + threadIdx.x;
  if (e >= NE) return;
  int d = dst[e], s = src[e];
  int p = rowp[d] + atomicAdd(&cur[d], 1);
  est[p] = (unsigned)s | ((unsigned)typ[e] << 28);
  ewt[p] = dis[d] * dis[s];
}

// ---------------- per-layer kernels ----------------
__global__ void k_prep0(const float* __restrict__ x, const float* __restrict__ emb,
                        unsigned short* __restrict__ Xh, unsigned short* __restrict__ Xl,
                        int xs) {
  int idx = blockIdx.x * blockDim.x + threadIdx.x;
  if (idx >= NN * 32) return;
  int r = idx >> 5, c4 = (idx & 31) * 4;
  const float* srcp = (r < N_X) ? (x + (size_t)r * 128 + c4)
                                : (emb + (size_t)(r - N_X) * 128 + c4);
  float4 hv = *(const float4*)srcp;
  float vv[4] = {hv.x, hv.y, hv.z, hv.w};
  unsigned hw[2], lw[2];
#pragma unroll
  for (int q = 0; q < 2; ++q) {
    unsigned short h0 = f2bf(vv[2 * q]), h1 = f2bf(vv[2 * q + 1]);
    unsigned short l0 = f2bf(vv[2 * q] - bf2f(h0)), l1 = f2bf(vv[2 * q + 1] - bf2f(h1));
    hw[q] = (unsigned)h0 | ((unsigned)h1 << 16);
    lw[q] = (unsigned)l0 | ((unsigned)l1 << 16);
  }
  size_t o = (size_t)r * xs + c4;
  *(uint2*)(Xh + o) = make_uint2(hw[0], hw[1]);
  *(uint2*)(Xl + o) = make_uint2(lw[0], lw[1]);
}

__global__ void k_prep(const float* __restrict__ H, const float* __restrict__ sc,
                       const float* __restrict__ sh, unsigned short* __restrict__ Xh,
                       unsigned short* __restrict__ Xl, int din, int logq, int xs) {
  int idx = blockIdx.x * blockDim.x + threadIdx.x;
  if (idx >= NN * (din >> 2)) return;
  int r = idx >> logq, c4 = (idx & ((din >> 2) - 1)) * 4;
  float4 hv = *(const float4*)(H + (size_t)r * din + c4);
  float vv[4] = {hv.x, hv.y, hv.z, hv.w};
  unsigned hw[2], lw[2];
#pragma unroll
  for (int q = 0; q < 4; ++q)
    vv[q] = fmaxf(vv[q] * sc[c4 + q] + sh[c4 + q], 0.f);
#pragma unroll
  for (int q = 0; q < 2; ++q) {
    unsigned short h0 = f2bf(vv[2 * q]), h1 = f2bf(vv[2 * q + 1]);
    unsigned short l0 = f2bf(vv[2 * q] - bf2f(h0)), l1 = f2bf(vv[2 * q + 1] - bf2f(h1));
    hw[q] = (unsigned)h0 | ((unsigned)h1 << 16);
    lw[q] = (unsigned)l0 | ((unsigned)l1 << 16);
  }
  size_t o = (size_t)r * xs + c4;
  *(uint2*)(Xh + o) = make_uint2(hw[0], hw[1]);
  *(uint2*)(Xl + o) = make_uint2(lw[0], lw[1]);
}

// one WAVE per node; L lanes per edge (L = din/8), 64/L edges in flight
template <int L>
__global__ void k_agg(unsigned short* __restrict__ Xh, unsigned short* __restrict__ Xl,
                      const int* __restrict__ rowp, const unsigned* __restrict__ est,
                      const float* __restrict__ ewt, int xs) {
  constexpr int G = 64 / L;
  constexpr int din = L * 8;
  const int wid = (blockIdx.x * 256 + threadIdx.x) >> 6;
  if (wid >= NN) return;
  const int lane = threadIdx.x & 63;
  const int grp = lane / L;
  const int j = lane & (L - 1);
  const int c0 = j * 8;
  const int beg = rowp[wid], end = rowp[wid + 1];
  float a0[8] = {}, a1[8] = {}, a2[8] = {};
  for (int i = beg + grp; i < end; i += G) {
    const unsigned st = est[i];
    const float wv = ewt[i];
    const size_t off = (size_t)(st & 0x0FFFFFFFu) * xs + c0;
    const unsigned t = st >> 28;
    uint4 hr = *(const uint4*)(Xh + off);
    uint4 lr = *(const uint4*)(Xl + off);
    float v[8];
    v[0] = bf2f(hr.x & 0xFFFFu) + bf2f(lr.x & 0xFFFFu);
    v[1] = bf2f(hr.x >> 16)     + bf2f(lr.x >> 16);
    v[2] = bf2f(hr.y & 0xFFFFu) + bf2f(lr.y & 0xFFFFu);
    v[3] = bf2f(hr.y >> 16)     + bf2f(lr.y >> 16);
    v[4] = bf2f(hr.z & 0xFFFFu) + bf2f(lr.z & 0xFFFFu);
    v[5] = bf2f(hr.z >> 16)     + bf2f(lr.z >> 16);
    v[6] = bf2f(hr.w & 0xFFFFu) + bf2f(lr.w & 0xFFFFu);
    v[7] = bf2f(hr.w >> 16)     + bf2f(lr.w >> 16);
    if (t == 0) {
#pragma unroll
      for (int q = 0; q < 8; ++q) a0[q] += wv * v[q];
    } else if (t == 1) {
#pragma unroll
      for (int q = 0; q < 8; ++q) a1[q] += wv * v[q];
    } else {
#pragma unroll
      for (int q = 0; q < 8; ++q) a2[q] += wv * v[q];
    }
  }
#pragma unroll
  for (int off = L; off < 64; off <<= 1) {
#pragma unroll
    for (int q = 0; q < 8; ++q) {
      a0[q] += __shfl_xor(a0[q], off);
      a1[q] += __shfl_xor(a1[q], off);
      a2[q] += __shfl_xor(a2[q], off);
    }
  }
  if (grp == 0) {
    const size_t ob = (size_t)wid * xs + din + c0;
    auto store8 = [&](const float* a, size_t o) {
      unsigned hw[4], lw[4];
#pragma unroll
      for (int q = 0; q < 4; ++q) {
        unsigned short h0 = f2bf(a[2 * q]), h1 = f2bf(a[2 * q + 1]);
        unsigned short l0 = f2bf(a[2 * q] - bf2f(h0)), l1 = f2bf(a[2 * q + 1] - bf2f(h1));
        hw[q] = (unsigned)h0 | ((unsigned)h1 << 16);
        lw[q] = (unsigned)l0 | ((unsigned)l1 << 16);
      }
      *(uint4*)(Xh + o) = make_uint4(hw[0], hw[1], hw[2], hw[3]);
      *(uint4*)(Xl + o) = make_uint4(lw[0], lw[1], lw[2], lw[3]);
    };
    store8(a0, ob);
    store8(a1, ob + din);
    store8(a2, ob + 2 * din);
  }
}

// WcT[n][k] hi/lo
__global__ void k_wcatT(const float* __restrict__ root, const float* __restrict__ W,
                        unsigned short* __restrict__ BhT, unsigned short* __restrict__ BlT,
                        int din, int dout) {
  int idx = blockIdx.x * blockDim.x + threadIdx.x;
  int K = 4 * din;
  if (idx >= dout * K) return;
  int n = idx / K, k = idx % K;
  float v = (k < din) ? root[(size_t)k * dout + n] : W[(size_t)(k - din) * dout + n];
  unsigned short h = f2bf(v);
  BhT[idx] = h;
  BlT[idx] = f2bf(v - bf2f(h));
}

// ---------------- split-f32 MFMA GEMM ----------------
// C = (Ah+Al) @ (Bh+Bl)^T + bias, tile 128 x BN, 4 waves (2x2)
// COALESCED global_load_lds staging: LDS chunk = [16 rows][64B]; lane l loads
// row (l>>2), 16B segment (l&3) -> 16 full 64B lines per instr.
// Fragment ds_read at r16*64 + kg*16: 64 distinct 16B slots -> conflict-free.
// Depth-2 prefetch, counted vmcnt; fused BN column stats in epilogue.
template <int BN>
__global__ __launch_bounds__(256, (BN == 128 ? 2 : 3)) void k_gemm_mfma(
    const unsigned short* __restrict__ Ah, const unsigned short* __restrict__ Al,
    const unsigned short* __restrict__ Bh, const unsigned short* __restrict__ Bl,
    const float* __restrict__ bias, float* __restrict__ C,
    float* __restrict__ bns, int M, int K, int Nc, int ny) {
  constexpr int NCHB = BN / 16;        // B chunks per plane
  constexpr int TC = 16 + 2 * NCHB;    // 1KB chunks per buffer
  constexpr int CPW = TC / 4;          // chunks staged per wave
  constexpr int NT = BN / 32;          // n-frags per wave
  __shared__ __align__(16) char lds[2][TC * 1024];

  const int tid = threadIdx.x;
  const int lane = tid & 63;
  const int w = tid >> 6;
  const int wm = w >> 1, wn = w & 1;
  const int r16 = lane & 15, kg = lane >> 4;

  // bijective XCD swizzle (m204)
  const int nwg = gridDim.x;
  const int q = nwg >> 3, r = nwg & 7;
  const int xcd = blockIdx.x & 7, pos = blockIdx.x >> 3;
  const int t = (xcd < r ? xcd * (q + 1) : r * (q + 1) + (xcd - r) * q) + pos;
  const int bm = (t / ny) * 128;
  const int bn = (t % ny) * BN;

  // coalesced per-lane staging source: row = row0 + lane/4, seg = lane%4
  const int rowseg = lane >> 2, seg = lane & 3;
  const unsigned short* gb[CPW];
#pragma unroll
  for (int i = 0; i < CPW; ++i) {
    int c = w * CPW + i;
    const unsigned short* base;
    int row0;
    if (c < 8)               { base = Ah; row0 = bm + c * 16; }
    else if (c < 16)         { base = Al; row0 = bm + (c - 8) * 16; }
    else if (c < 16 + NCHB)  { base = Bh; row0 = bn + (c - 16) * 16; }
    else                     { base = Bl; row0 = bn + (c - 16 - NCHB) * 16; }
    gb[i] = base + (size_t)(row0 + rowseg) * K + seg * 8;
  }

  floatx4 acc[4][NT];
#pragma unroll
  for (int i = 0; i < 4; ++i)
#pragma unroll
    for (int jj = 0; jj < NT; ++jj) acc[i][jj] = (floatx4)0.f;

  const int nk = K >> 5;

  auto stage = [&](int b, int tk) {
#pragma unroll
    for (int i = 0; i < CPW; ++i)
      __builtin_amdgcn_global_load_lds((gv_t*)(gb[i] + tk * 32),
                                       (lv_t*)&lds[b][(w * CPW + i) * 1024],
                                       16, 0, 0);
  };

  stage(0, 0);
  stage(1, 1);

  const int fo = r16 * 64 + kg * 16;   // fragment byte offset within chunk

  int buf = 0;
  for (int tk = 0; tk < nk; ++tk) {
    if (tk < nk - 1) {
      if constexpr (CPW == 6)       asm volatile("s_waitcnt vmcnt(6)" ::: "memory");
      else                          asm volatile("s_waitcnt vmcnt(8)" ::: "memory");
    } else {
      asm volatile("s_waitcnt vmcnt(0)" ::: "memory");
    }
    __builtin_amdgcn_s_barrier();

    const char* Lb = lds[buf];
    short8 ah[4], al[4], bh[NT], bl[NT];
#pragma unroll
    for (int mt = 0; mt < 4; ++mt) {
      ah[mt] = *(const short8*)(Lb + (wm * 4 + mt) * 1024 + fo);
      al[mt] = *(const short8*)(Lb + (8 + wm * 4 + mt) * 1024 + fo);
    }
#pragma unroll
    for (int nt = 0; nt < NT; ++nt) {
      bh[nt] = *(const short8*)(Lb + (16 + wn * NT + nt) * 1024 + fo);
      bl[nt] = *(const short8*)(Lb + (16 + NCHB + wn * NT + nt) * 1024 + fo);
    }

    __builtin_amdgcn_s_setprio(1);
#pragma unroll
    for (int mt = 0; mt < 4; ++mt)
#pragma unroll
      for (int nt = 0; nt < NT; ++nt) {
        acc[mt][nt] = __builtin_amdgcn_mfma_f32_16x16x32_bf16(ah[mt], bh[nt], acc[mt][nt], 0, 0, 0);
        acc[mt][nt] = __builtin_amdgcn_mfma_f32_16x16x32_bf16(ah[mt], bl[nt], acc[mt][nt], 0, 0, 0);
        acc[mt][nt] = __builtin_amdgcn_mfma_f32_16x16x32_bf16(al[mt], bh[nt], acc[mt][nt], 0, 0, 0);
      }
    __builtin_amdgcn_s_setprio(0);

    __builtin_amdgcn_s_barrier();     // all waves done reading lds[buf]
    if (tk + 2 < nk) stage(buf, tk + 2);
    buf ^= 1;
  }

  // epilogue: D row = (lane>>4)*4 + reg, col = lane&15; fused BN col stats
  float s[NT], s2[NT];
#pragma unroll
  for (int nt = 0; nt < NT; ++nt) { s[nt] = 0.f; s2[nt] = 0.f; }
#pragma unroll
  for (int mt = 0; mt < 4; ++mt) {
    const int gr0 = bm + wm * 64 + mt * 16 + kg * 4;
#pragma unroll
    for (int nt = 0; nt < NT; ++nt) {
      const int col = bn + wn * (NT * 16) + nt * 16 + r16;
      const float bv = bias[col];
#pragma unroll
      for (int rr = 0; rr < 4; ++rr) {
        const int gr = gr0 + rr;
        if (gr < M) {
          const float o = acc[mt][nt][rr] + bv;
          C[(size_t)gr * Nc + col] = o;
          s[nt] += o;
          s2[nt] += o * o;
        }
      }
    }
  }
  if (bns) {
#pragma unroll
    for (int nt = 0; nt < NT; ++nt) {
      float a = s[nt], b2 = s2[nt];
      a += __shfl_xor(a, 16); a += __shfl_xor(a, 32);
      b2 += __shfl_xor(b2, 16); b2 += __shfl_xor(b2, 32);
      if (kg == 0) {
        const int col = bn + wn * (NT * 16) + nt * 16 + r16;
        atomicAdd(&bns[col], a);
        atomicAdd(&bns[Nc + col], b2);
      }
    }
  }
}

__global__ void k_bnfinal(const float* __restrict__ sums, const float* __restrict__ g,
                          const float* __restrict__ b, float* __restrict__ sc,
                          float* __restrict__ sh, int d) {
  int c = threadIdx.x;
  if (c >= d) return;
  float mean = sums[c] * (1.f / NN);
  float var = sums[d + c] * (1.f / NN) - mean * mean;
  float rs = rsqrtf(var + 1e-5f);
  float s = rs * g[c];
  sc[c] = s;
  sh[c] = b[c] - mean * s;
}

// ---------------- host driver ----------------
extern "C" void kernel_launch(void* const* d_in, const int* in_sizes, int n_in,
                              void* d_out, int out_size, void* d_ws, size_t ws_size,
                              hipStream_t stream) {
  const float* x   = (const float*)d_in[0];
  const float* emb = (const float*)d_in[1];
  const float* conv_w[4] = {(const float*)d_in[2], (const float*)d_in[5],
                            (const float*)d_in[8], (const float*)d_in[11]};
  const float* conv_r[4] = {(const float*)d_in[3], (const float*)d_in[6],
                            (const float*)d_in[9], (const float*)d_in[12]};
  const float* conv_b[4] = {(const float*)d_in[4], (const float*)d_in[7],
                            (const float*)d_in[10], (const float*)d_in[13]};
  const float* n1g = (const float*)d_in[14];
  const float* n1b = (const float*)d_in[15];
  const float* n2g = (const float*)d_in[16];
  const float* n2b = (const float*)d_in[17];
  const int* eidx = (const int*)d_in[18];
  const int* etyp = (const int*)d_in[19];
  const int* dst  = eidx;
  const int* srcp = eidx + NE;
  float* out = (float*)d_out;

  char* w = (char*)d_ws;
  auto alloc = [&](size_t bytes) {
    char* p = w;
    w += (bytes + 255) & ~(size_t)255;
    return p;
  };
  unsigned short* Xh  = (unsigned short*)alloc((size_t)MPAD * 1024 * 2);
  unsigned short* Xl  = (unsigned short*)alloc((size_t)MPAD * 1024 * 2);
  float*    H    = (float*)alloc((size_t)NN * 256 * 4);
  unsigned short* WcTh = (unsigned short*)alloc((size_t)256 * 1024 * 2);
  unsigned short* WcTl = (unsigned short*)alloc((size_t)256 * 1024 * 2);
  float*    bns  = (float*)alloc(512 * 4);
  float*    bsc  = (float*)alloc(256 * 4);
  float*    bsh  = (float*)alloc(256 * 4);
  float*    dis  = (float*)alloc((size_t)NN * 4);
  int*      deg  = (int*)alloc((size_t)NN * 4);
  int*      rowp = (int*)alloc((size_t)(NN + 1) * 4);
  int*      cur  = (int*)alloc((size_t)NN * 4);
  int*      bsum = (int*)alloc(64 * 4);
  unsigned* est  = (unsigned*)alloc((size_t)NE * 4);
  float*    ewt  = (float*)alloc((size_t)NE * 4);

  hipMemsetAsync(deg, 0, (size_t)NN * 4, stream);
  hipMemsetAsync(cur, 0, (size_t)NN * 4, stream);
  k_deg<<<(NE + 255) / 256, 256, 0, stream>>>(dst, deg);
  k_dis<<<(NN + 255) / 256, 256, 0, stream>>>(deg, dis);
  k_scan1<<<SCAN_NB, SCAN_B, 0, stream>>>(deg, rowp, bsum);
  k_scan2<<<1, 64, 0, stream>>>(bsum);
  k_scan3<<<(NN + 255) / 256, 256, 0, stream>>>(rowp, bsum);
  k_build<<<(NE + 255) / 256, 256, 0, stream>>>(dst, srcp, etyp, dis, rowp, cur, est, ewt);

  const int din_a[8]  = {128, 128, 256, 256, 256, 256, 256, 256};
  const int dout_a[8] = {128, 256, 256, 256, 256, 256, 256, 64};
  const int wi_a[8]   = {0, 1, 2, 2, 2, 2, 2, 3};
  const int gm = (NN + 127) / 128;   // 391

  for (int l = 0; l < 8; ++l) {
    const int din = din_a[l], dout = dout_a[l];
    const int K = 4 * din, xs = K;
    const int wi = wi_a[l];

    if (l == 0)
      k_prep0<<<(NN * 32 + 255) / 256, 256, 0, stream>>>(x, emb, Xh, Xl, xs);
    else
      k_prep<<<(NN * (din >> 2) + 255) / 256, 256, 0, stream>>>(
          H, bsc, bsh, Xh, Xl, din, (din == 128 ? 5 : 6), xs);

    if (din == 128)
      k_agg<16><<<(NN + 3) / 4, 256, 0, stream>>>(Xh, Xl, rowp, est, ewt, xs);
    else
      k_agg<32><<<(NN + 3) / 4, 256, 0, stream>>>(Xh, Xl, rowp, est, ewt, xs);

    k_wcatT<<<(dout * K + 255) / 256, 256, 0, stream>>>(conv_r[wi], conv_w[wi], WcTh, WcTl, din, dout);

    if (l < 7) hipMemsetAsync(bns, 0, (size_t)2 * dout * 4, stream);

    float* C = (l == 7) ? out : H;
    float* bstat = (l == 7) ? nullptr : bns;
    if (dout == 64)
      k_gemm_mfma<64><<<gm, 256, 0, stream>>>(Xh, Xl, WcTh, WcTl, conv_b[wi], C, bstat, NN, K, dout, 1);
    else {
      const int ny = dout / 128;
      k_gemm_mfma<128><<<gm * ny, 256, 0, stream>>>(Xh, Xl, WcTh, WcTl, conv_b[wi], C, bstat, NN, K, dout, ny);
    }

    if (l < 7)
      k_bnfinal<<<1, 256, 0, stream>>>(bns, (l == 0) ? n1g : n2g,
                                       (l == 0) ? n1b : n2b, bsc, bsh, dout);
  }
}